// Round 1
// baseline (228.420 us; speedup 1.0000x reference)
//
#include <hip/hip_runtime.h>
#include <math.h>

// Problem constants (fixed by reference): B=4, S=2048, D=512, H=8, R=8, dk=64
#define B_ 4
#define S_ 2048
#define D_ 512
#define H_ 8
#define R_ 8
#define DK_ 64
#define NEDGE (B_*H_*2*R_*S_)   // 1,048,576
#define EPB   (2*R_*S_)         // 32768 edges per (b,h)
#define ELLCAP 64               // max in-degree slots; Poisson(15) tail ~2e-8
#define SCALE_ (1.0f/24.0f)     // 1/(3*sqrt(dk))

typedef __attribute__((ext_vector_type(8))) short bf16x8;
typedef __attribute__((ext_vector_type(8))) unsigned short ushort8_t;
typedef __attribute__((ext_vector_type(4))) float f32x4;

#define AS1q const __attribute__((address_space(1)))
#define AS3q __attribute__((address_space(3)))

__device__ inline unsigned short f2bf(float f) {
    unsigned u = __builtin_bit_cast(unsigned, f);
    u += 0x7fffu + ((u >> 16) & 1u);   // RNE (no NaN inputs here)
    return (unsigned short)(u >> 16);
}
__device__ inline float bf2f(unsigned short u) {
    return __builtin_bit_cast(float, ((unsigned)u) << 16);
}

// ---------------- fused prep: qkv + W converts ------------------------------
__global__ __launch_bounds__(256) void prep(
    const float* __restrict__ query, const float* __restrict__ key,
    const float* __restrict__ value,
    const float* __restrict__ Wq, const float* __restrict__ Wk,
    const float* __restrict__ Wv, const float* __restrict__ Wo,
    unsigned short* __restrict__ qc, unsigned short* __restrict__ kc,
    unsigned short* __restrict__ vc,
    unsigned short* __restrict__ wqb, unsigned short* __restrict__ wkb,
    unsigned short* __restrict__ wvb, unsigned short* __restrict__ wob)
{
    int bid = blockIdx.x;
    const float* x;
    unsigned short* y;
    size_t i;
    if (bid < 12288) {
        int z = bid >> 12;                 // 0..2
        x = (z == 0) ? query : (z == 1) ? key : value;
        y = (z == 0) ? qc : (z == 1) ? kc : vc;
        i = ((size_t)(bid & 4095) * 256 + threadIdx.x) * 4;
    } else {
        int r = bid - 12288;
        int z = r >> 8;                    // 0..3
        x = (z == 0) ? Wq : (z == 1) ? Wk : (z == 2) ? Wv : Wo;
        y = (z == 0) ? wqb : (z == 1) ? wkb : (z == 2) ? wvb : wob;
        i = ((size_t)(r & 255) * 256 + threadIdx.x) * 4;
    }
    float4 v = *(const float4*)&x[i];
    *(ushort4*)&y[i] = make_ushort4(f2bf(v.x), f2bf(v.y), f2bf(v.z), f2bf(v.w));
}

// ---------------- bf16 GEMM, m97-style: global_load_lds + XOR-swizzled LDS --
template<int TN>
__global__ __launch_bounds__(256) void gemm_bf16(
    const unsigned short* __restrict__ A0, const unsigned short* __restrict__ A1,
    const unsigned short* __restrict__ A2,
    const unsigned short* __restrict__ W0, const unsigned short* __restrict__ W1,
    const unsigned short* __restrict__ W2,
    const float* __restrict__ bi0, const float* __restrict__ bi1, const float* __restrict__ bi2,
    unsigned short* __restrict__ C0, unsigned short* __restrict__ C1,
    unsigned short* __restrict__ C2,
    float* __restrict__ Cf, int a_bhsd)
{
    constexpr int NFR = TN / 32;           // B frags per wave (4 or 2)
    __shared__ unsigned short As[128 * 64];
    __shared__ unsigned short Bs[TN * 64];
    const int z = blockIdx.z;
    const unsigned short* A = (z == 0) ? A0 : (z == 1) ? A1 : A2;
    const unsigned short* W = (z == 0) ? W0 : (z == 1) ? W1 : W2;
    const float* bias        = (z == 0) ? bi0 : (z == 1) ? bi1 : bi2;
    unsigned short* C        = (z == 0) ? C0 : (z == 1) ? C1 : C2;

    const int t    = threadIdx.x;
    const int lane = t & 63;
    const int w    = t >> 6;
    const int wm   = w >> 1, wn = w & 1;
    const int m0   = blockIdx.x * 128;
    const int n0   = blockIdx.y * TN;

    const int lr    = lane >> 3;           // row within 8-row stage chunk
    const int cglob = (lane & 7) ^ lr;     // swizzled global source chunk

    f32x4 acc[4][NFR] = {};

    for (int kk = 0; kk < D_; kk += 64) {
        #pragma unroll
        for (int i = 0; i < 4; ++i) {
            int rowl = w * 32 + i * 8;         // wave-uniform LDS row base
            int m = m0 + rowl + lr;
            const unsigned short* ga;
            if (a_bhsd) {
                int b = m >> 11, s = m & (S_ - 1), h = kk >> 6;
                ga = A + ((((size_t)b * H_ + h) * S_ + s) << 6) + cglob * 8;
            } else {
                ga = A + (size_t)m * D_ + kk + cglob * 8;
            }
            __builtin_amdgcn_global_load_lds((AS1q unsigned*)ga,
                (AS3q unsigned*)(As + rowl * 64), 16, 0, 0);
        }
        #pragma unroll
        for (int i = 0; i < TN / 32; ++i) {
            int rowl = w * (TN / 4) + i * 8;
            const unsigned short* gb =
                W + (size_t)(n0 + rowl + lr) * D_ + kk + cglob * 8;
            __builtin_amdgcn_global_load_lds((AS1q unsigned*)gb,
                (AS3q unsigned*)(Bs + rowl * 64), 16, 0, 0);
        }
        __syncthreads();

        #pragma unroll
        for (int ks = 0; ks < 64; ks += 32) {
            const int c0 = ks >> 3;            // 0 or 4
            bf16x8 af[4], bfr[NFR];
            #pragma unroll
            for (int mi = 0; mi < 4; ++mi) {
                int row = wm * 64 + mi * 16 + (lane & 15);
                int cp  = (c0 + (lane >> 4)) ^ (lane & 7);
                af[mi] = *(const bf16x8*)&As[row * 64 + cp * 8];
            }
            #pragma unroll
            for (int nj = 0; nj < NFR; ++nj) {
                int row = wn * (TN / 2) + nj * 16 + (lane & 15);
                int cp  = (c0 + (lane >> 4)) ^ (lane & 7);
                bfr[nj] = *(const bf16x8*)&Bs[row * 64 + cp * 8];
            }
            #pragma unroll
            for (int mi = 0; mi < 4; ++mi)
                #pragma unroll
                for (int nj = 0; nj < NFR; ++nj)
                    acc[mi][nj] = __builtin_amdgcn_mfma_f32_16x16x32_bf16(af[mi], bfr[nj], acc[mi][nj], 0, 0, 0);
        }
        __syncthreads();
    }

    // epilogue: C/D layout col = lane&15, row = (lane>>4)*4 + reg
    #pragma unroll
    for (int mi = 0; mi < 4; ++mi) {
        #pragma unroll
        for (int nj = 0; nj < NFR; ++nj) {
            #pragma unroll
            for (int r = 0; r < 4; ++r) {
                int m = m0 + wm * 64 + mi * 16 + (lane >> 4) * 4 + r;
                int n = n0 + wn * (TN / 2) + nj * 16 + (lane & 15);
                float val = acc[mi][nj][r] + bias[n];
                if (Cf) {
                    Cf[(size_t)m * D_ + n] = val;
                } else {
                    int b = m >> 11, s = m & (S_ - 1);
                    int h = n >> 6,  d = n & 63;
                    C[((((size_t)b * H_ + h) * S_ + s) << 6) + d] = f2bf(val);
                }
            }
        }
    }
}

// ---------------- rank-1 score-term tables ----------------------------------
// qrk[node][r2] = (q[node] . rel_k[h][r2]) / 24 ; rqk[node][r2] = (rel_q[h][r2] . k[node]) / 24
// node = ((b*H+h)<<11)+s over 64K nodes, r2 in [0,16). One wave per 16-node
// chunk (chunk never crosses an h boundary), rel rows hoisted to registers.
__global__ __launch_bounds__(256) void rel_dots(
    const unsigned short* __restrict__ q, const unsigned short* __restrict__ k_,
    const float* __restrict__ rel_q, const float* __restrict__ rel_k,
    float* __restrict__ qrk, float* __restrict__ rqk)
{
    const int t    = threadIdx.x;
    const int lane = t & 63;
    const int sub  = lane & 7;           // dk chunk (8 elems)
    const int grp  = lane >> 3;          // r2 within half
    const int wid  = (blockIdx.x << 2) + (t >> 6);   // 0..4095
    const int n0   = wid << 4;                        // base node (16/wave)
    const int h    = (n0 >> 11) & 7;

    float rkv[2][8], rqv[2][8];
    #pragma unroll
    for (int pp = 0; pp < 2; ++pp) {
        const float* a = rel_k + (size_t)(((h << 4) + grp + pp * 8) << 6) + sub * 8;
        const float* b = rel_q + (size_t)(((h << 4) + grp + pp * 8) << 6) + sub * 8;
        f32x4 a0 = *(const f32x4*)a, a1 = *(const f32x4*)(a + 4);
        f32x4 b0 = *(const f32x4*)b, b1 = *(const f32x4*)(b + 4);
        #pragma unroll
        for (int i = 0; i < 4; ++i) {
            rkv[pp][i] = a0[i]; rkv[pp][4 + i] = a1[i];
            rqv[pp][i] = b0[i]; rqv[pp][4 + i] = b1[i];
        }
    }
    for (int i = 0; i < 16; ++i) {
        int node = n0 + i;
        ushort8_t q8 = *(const ushort8_t*)&q [((size_t)node << 6) + sub * 8];
        ushort8_t k8 = *(const ushort8_t*)&k_[((size_t)node << 6) + sub * 8];
        float qv[8], kv[8];
        #pragma unroll
        for (int e = 0; e < 8; ++e) { qv[e] = bf2f(q8[e]); kv[e] = bf2f(k8[e]); }
        #pragma unroll
        for (int pp = 0; pp < 2; ++pp) {
            float a = 0.f, b = 0.f;
            #pragma unroll
            for (int e = 0; e < 8; ++e) {
                a = fmaf(qv[e], rkv[pp][e], a);
                b = fmaf(kv[e], rqv[pp][e], b);
            }
            a += __shfl_xor(a, 1); a += __shfl_xor(a, 2); a += __shfl_xor(a, 4);
            b += __shfl_xor(b, 1); b += __shfl_xor(b, 2); b += __shfl_xor(b, 4);
            if (sub == 0) {
                qrk[((size_t)node << 4) + grp + pp * 8] = a * SCALE_;
                rqk[((size_t)node << 4) + grp + pp * 8] = b * SCALE_;
            }
        }
    }
}

// ---------------- fused ELL-build + score+softmax+aggregate -----------------
// One block per (bh, 128-dst window). Scan phase skips the always-masked
// r2==0 range and reads edge indices as int2. Gather phase: slimmed loop —
// score is only q.k (rank-1 terms come from the precomputed tables: qrk via
// per-dst register row + shfl, rqk via 4B L2 gather), rel_v read as f32
// directly from the input (L1-resident), o-accum avoids its conversions.
__global__ __launch_bounds__(1024) void attn_fused(
    const unsigned short* __restrict__ q, const unsigned short* __restrict__ k_,
    const unsigned short* __restrict__ v_,
    const float* __restrict__ qrk, const float* __restrict__ rqk,
    const float* __restrict__ rel_v,
    const int* __restrict__ start_nodes, const int* __restrict__ end_nodes,
    unsigned short* __restrict__ attn)
{
    __shared__ unsigned short ell[128 * ELLCAP];   // 16 KB
    __shared__ int cnt[128];
    const int bi  = blockIdx.x;          // 512 blocks
    const int xcd = bi & 7;
    const int loc = bi >> 3;             // 0..63
    const int bh  = xcd * 4 + (loc >> 4);
    const int dlo = (loc & 15) << 7;     // 128-dst window base
    const int t   = threadIdx.x;

    if (t < 128) cnt[t] = 0;
    __syncthreads();

    // ---- scan phase: coalesced int2 read of this bh's edge lists ----
    const int base_idx = bh * (R_ * S_);
    for (int f = S_ + t * 2; f < EPB; f += 2048) {   // 15 iterations, r2>=1
        int r2 = f >> 11;
        int s  = f & (S_ - 1);                        // even
        int idx = base_idx + ((r2 & 7) << 11) + s;
        int2 sn2 = *(const int2*)&start_nodes[idx];
        int2 en2 = *(const int2*)&end_nodes[idx];
        #pragma unroll
        for (int u = 0; u < 2; ++u) {
            int sn = u ? sn2.y : sn2.x;
            if (sn == -1) continue;                   // padded edge
            int en = u ? en2.y : en2.x;
            int dst = (r2 < R_) ? en : sn;
            unsigned rel = (unsigned)(dst - dlo);
            if (rel < 128u) {
                int ki = (r2 < R_) ? sn : en;
                int pos = atomicAdd(&cnt[rel], 1);
                if (pos < ELLCAP)
                    ell[(rel << 6) + pos] = (unsigned short)((r2 << 11) | ki);
            }
        }
    }
    __syncthreads();

    // ---- gather phase: wave w handles dsts dlo + dd*16 + w ----
    const int w    = t >> 6;
    const int lane = t & 63;
    const int grp  = lane >> 3;          // edge slot within group-of-8
    const int sub  = lane & 7;           // dk chunk (8 elems)
    const int h    = bh & 7;
    const size_t node_base = ((size_t)bh << 11);
    const float* qrk_bh = qrk + (node_base << 4);
    const float* rqk_bh = rqk + (node_base << 4);
    const float* rvh    = rel_v + ((size_t)(h << 4) << 6);   // [16][64] f32

    for (int dd = 0; dd < 8; ++dd) {
        int dl  = dd * 16 + w;           // 0..127
        int dst = dlo + dl;

        ushort8_t q8 = *(const ushort8_t*)&q[((node_base + dst) << 6) + sub * 8];
        float qv[8];
        #pragma unroll
        for (int i = 0; i < 8; ++i) qv[i] = bf2f(q8[i]);
        float qrk_l = qrk_bh[((size_t)dst << 4) + (lane & 15)];  // lanes 0..15 hold r2 row

        int n = cnt[dl];
        if (n > ELLCAP) n = ELLCAP;
        int d_all = (int)ell[(dl << 6) + lane];   // LDS row, 2-way free

        float den = 0.f;
        float o[8] = {};
        #pragma unroll 2
        for (int j = 0; j < n; j += 8) {
            int slot = j + grp;
            int d = __shfl(d_all, slot);
            bool valid = slot < n;
            int ki = d & (S_ - 1);
            int r2 = (d >> 11) & 15;
            ushort8_t k8 = *(const ushort8_t*)&k_[((node_base + ki) << 6) + sub * 8];
            float p = 0.f;
            #pragma unroll
            for (int i = 0; i < 8; ++i)
                p = fmaf(bf2f(k8[i]), qv[i], p);
            p += __shfl_xor(p, 1);
            p += __shfl_xor(p, 2);
            p += __shfl_xor(p, 4);
            float tb = __shfl(qrk_l, r2) + rqk_bh[((size_t)ki << 4) + r2];
            float sf = valid ? __expf(fmaf(p, SCALE_, tb)) : 0.f;
            ushort8_t v8 = *(const ushort8_t*)&v_[((node_base + ki) << 6) + sub * 8];
            const float* rvp = rvh + (r2 << 6) + sub * 8;
            f32x4 rv0 = *(const f32x4*)rvp;
            f32x4 rv1 = *(const f32x4*)(rvp + 4);
            den += sf;
            #pragma unroll
            for (int i = 0; i < 4; ++i)
                o[i] = fmaf(sf, bf2f(v8[i]) + rv0[i], o[i]);
            #pragma unroll
            for (int i = 0; i < 4; ++i)
                o[4 + i] = fmaf(sf, bf2f(v8[4 + i]) + rv1[i], o[4 + i]);
        }
        // cross-group reduction (xor 8,16,32 preserves sub)
        den += __shfl_xor(den, 8); den += __shfl_xor(den, 16); den += __shfl_xor(den, 32);
        #pragma unroll
        for (int i = 0; i < 8; ++i) {
            o[i] += __shfl_xor(o[i], 8);
            o[i] += __shfl_xor(o[i], 16);
            o[i] += __shfl_xor(o[i], 32);
        }
        if (grp == 0) {
            float inv = (den > 0.f) ? 1.0f / den : 0.f;
            ushort8_t r;
            #pragma unroll
            for (int i = 0; i < 8; ++i) r[i] = f2bf(o[i] * inv);
            *(ushort8_t*)&attn[((node_base + dst) << 6) + sub * 8] = r;
        }
    }
}

extern "C" void kernel_launch(void* const* d_in, const int* in_sizes, int n_in,
                              void* d_out, int out_size, void* d_ws, size_t ws_size,
                              hipStream_t stream) {
    const float* query = (const float*)d_in[0];
    const float* key   = (const float*)d_in[1];
    const float* value = (const float*)d_in[2];
    const int* start_nodes = (const int*)d_in[3];
    const int* end_nodes   = (const int*)d_in[4];
    const float* rel_q = (const float*)d_in[5];
    const float* rel_k = (const float*)d_in[6];
    const float* rel_v = (const float*)d_in[7];
    const float* Wq = (const float*)d_in[8];
    const float* bq = (const float*)d_in[9];
    const float* Wk = (const float*)d_in[10];
    const float* bk = (const float*)d_in[11];
    const float* Wv = (const float*)d_in[12];
    const float* bv = (const float*)d_in[13];
    const float* Wo = (const float*)d_in[14];
    const float* bo = (const float*)d_in[15];
    float* out = (float*)d_out;

    const size_t NQ = (size_t)B_ * H_ * S_ * DK_;   // 4,194,304
    const size_t NW = (size_t)D_ * D_;              // 262,144
    unsigned short* p = (unsigned short*)d_ws;
    unsigned short* qc = p;            p += NQ;
    unsigned short* kc = p;            p += NQ;
    unsigned short* vc = p;            p += NQ;
    unsigned short* q  = p;            p += NQ;
    unsigned short* k  = p;            p += NQ;
    unsigned short* v  = p;            p += NQ;
    unsigned short* attn = p;          p += NQ;
    unsigned short* wqb = p;           p += NW;
    unsigned short* wkb = p;           p += NW;
    unsigned short* wvb = p;           p += NW;
    unsigned short* wob = p;           p += NW;
    // score-term tables alias qc (dead after GEMM1): 2 x 1M f32 = 8 MB = |qc|
    float* qrk = (float*)qc;
    float* rqk = qrk + ((size_t)1 << 20);

    // 1) fused converts (one dispatch)
    prep<<<13312, 256, 0, stream>>>(query, key, value, Wq, Wk, Wv, Wo,
                                    qc, kc, vc, wqb, wkb, wvb, wob);

    // 2) fused QKV projection (128x128 tiles, 768 blocks)
    dim3 ggrid(B_ * S_ / 128, D_ / 128, 3);
    gemm_bf16<128><<<ggrid, 256, 0, stream>>>(qc, kc, vc, wqb, wkb, wvb, bq, bk, bv,
                                              q, k, v, nullptr, 0);

    // 3) rank-1 score-term tables (q.rel_k, rel_q.k), prescaled by 1/24
    rel_dots<<<1024, 256, 0, stream>>>(q, k, rel_q, rel_k, qrk, rqk);

    // 4) fused ELL-build + attention (no global ELL)
    attn_fused<<<512, 1024, 0, stream>>>(q, k, v, qrk, rqk, rel_v,
                                         start_nodes, end_nodes, attn);

    // 5) output projection (128x64 tiles -> 512 blocks = 2/CU, fp32 out)
    dim3 ogrid(B_ * S_ / 128, D_ / 64, 1);
    gemm_bf16<64><<<ogrid, 256, 0, stream>>>(attn, attn, attn, wob, wob, wob, bo, bo, bo,
                                             nullptr, nullptr, nullptr, out, 1);
}

// Round 2
// 215.785 us; speedup vs baseline: 1.0586x; 1.0586x over previous
//
#include <hip/hip_runtime.h>
#include <math.h>

// Problem constants (fixed by reference): B=4, S=2048, D=512, H=8, R=8, dk=64
#define B_ 4
#define S_ 2048
#define D_ 512
#define H_ 8
#define R_ 8
#define DK_ 64
#define NEDGE (B_*H_*2*R_*S_)   // 1,048,576
#define EPB   (2*R_*S_)         // 32768 edges per (b,h)
#define ELLCAP 64               // max in-degree slots; Poisson(15) tail ~2e-8
#define SCALE_ (1.0f/24.0f)     // 1/(3*sqrt(dk))

typedef __attribute__((ext_vector_type(8))) short bf16x8;
typedef __attribute__((ext_vector_type(8))) unsigned short ushort8_t;
typedef __attribute__((ext_vector_type(4))) float f32x4;

#define AS1q const __attribute__((address_space(1)))
#define AS3q __attribute__((address_space(3)))

__device__ inline unsigned short f2bf(float f) {
    unsigned u = __builtin_bit_cast(unsigned, f);
    u += 0x7fffu + ((u >> 16) & 1u);   // RNE (no NaN inputs here)
    return (unsigned short)(u >> 16);
}
__device__ inline float bf2f(unsigned short u) {
    return __builtin_bit_cast(float, ((unsigned)u) << 16);
}

// ---------------- fused prep: qkv + W converts ------------------------------
__global__ __launch_bounds__(256) void prep(
    const float* __restrict__ query, const float* __restrict__ key,
    const float* __restrict__ value,
    const float* __restrict__ Wq, const float* __restrict__ Wk,
    const float* __restrict__ Wv, const float* __restrict__ Wo,
    unsigned short* __restrict__ qc, unsigned short* __restrict__ kc,
    unsigned short* __restrict__ vc,
    unsigned short* __restrict__ wqb, unsigned short* __restrict__ wkb,
    unsigned short* __restrict__ wvb, unsigned short* __restrict__ wob)
{
    int bid = blockIdx.x;
    const float* x;
    unsigned short* y;
    size_t i;
    if (bid < 12288) {
        int z = bid >> 12;                 // 0..2
        x = (z == 0) ? query : (z == 1) ? key : value;
        y = (z == 0) ? qc : (z == 1) ? kc : vc;
        i = ((size_t)(bid & 4095) * 256 + threadIdx.x) * 4;
    } else {
        int r = bid - 12288;
        int z = r >> 8;                    // 0..3
        x = (z == 0) ? Wq : (z == 1) ? Wk : (z == 2) ? Wv : Wo;
        y = (z == 0) ? wqb : (z == 1) ? wkb : (z == 2) ? wvb : wob;
        i = ((size_t)(r & 255) * 256 + threadIdx.x) * 4;
    }
    float4 v = *(const float4*)&x[i];
    *(ushort4*)&y[i] = make_ushort4(f2bf(v.x), f2bf(v.y), f2bf(v.z), f2bf(v.w));
}

// ---------------- bf16 GEMM, m97-style: global_load_lds + XOR-swizzled LDS --
template<int TN>
__global__ __launch_bounds__(256) void gemm_bf16(
    const unsigned short* __restrict__ A0, const unsigned short* __restrict__ A1,
    const unsigned short* __restrict__ A2,
    const unsigned short* __restrict__ W0, const unsigned short* __restrict__ W1,
    const unsigned short* __restrict__ W2,
    const float* __restrict__ bi0, const float* __restrict__ bi1, const float* __restrict__ bi2,
    unsigned short* __restrict__ C0, unsigned short* __restrict__ C1,
    unsigned short* __restrict__ C2,
    float* __restrict__ Cf, int a_bhsd)
{
    constexpr int NFR = TN / 32;           // B frags per wave (4 or 2)
    __shared__ unsigned short As[128 * 64];
    __shared__ unsigned short Bs[TN * 64];
    const int z = blockIdx.z;
    const unsigned short* A = (z == 0) ? A0 : (z == 1) ? A1 : A2;
    const unsigned short* W = (z == 0) ? W0 : (z == 1) ? W1 : W2;
    const float* bias        = (z == 0) ? bi0 : (z == 1) ? bi1 : bi2;
    unsigned short* C        = (z == 0) ? C0 : (z == 1) ? C1 : C2;

    const int t    = threadIdx.x;
    const int lane = t & 63;
    const int w    = t >> 6;
    const int wm   = w >> 1, wn = w & 1;
    const int m0   = blockIdx.x * 128;
    const int n0   = blockIdx.y * TN;

    const int lr    = lane >> 3;           // row within 8-row stage chunk
    const int cglob = (lane & 7) ^ lr;     // swizzled global source chunk

    f32x4 acc[4][NFR] = {};

    for (int kk = 0; kk < D_; kk += 64) {
        #pragma unroll
        for (int i = 0; i < 4; ++i) {
            int rowl = w * 32 + i * 8;         // wave-uniform LDS row base
            int m = m0 + rowl + lr;
            const unsigned short* ga;
            if (a_bhsd) {
                int b = m >> 11, s = m & (S_ - 1), h = kk >> 6;
                ga = A + ((((size_t)b * H_ + h) * S_ + s) << 6) + cglob * 8;
            } else {
                ga = A + (size_t)m * D_ + kk + cglob * 8;
            }
            __builtin_amdgcn_global_load_lds((AS1q unsigned*)ga,
                (AS3q unsigned*)(As + rowl * 64), 16, 0, 0);
        }
        #pragma unroll
        for (int i = 0; i < TN / 32; ++i) {
            int rowl = w * (TN / 4) + i * 8;
            const unsigned short* gb =
                W + (size_t)(n0 + rowl + lr) * D_ + kk + cglob * 8;
            __builtin_amdgcn_global_load_lds((AS1q unsigned*)gb,
                (AS3q unsigned*)(Bs + rowl * 64), 16, 0, 0);
        }
        __syncthreads();

        #pragma unroll
        for (int ks = 0; ks < 64; ks += 32) {
            const int c0 = ks >> 3;            // 0 or 4
            bf16x8 af[4], bfr[NFR];
            #pragma unroll
            for (int mi = 0; mi < 4; ++mi) {
                int row = wm * 64 + mi * 16 + (lane & 15);
                int cp  = (c0 + (lane >> 4)) ^ (lane & 7);
                af[mi] = *(const bf16x8*)&As[row * 64 + cp * 8];
            }
            #pragma unroll
            for (int nj = 0; nj < NFR; ++nj) {
                int row = wn * (TN / 2) + nj * 16 + (lane & 15);
                int cp  = (c0 + (lane >> 4)) ^ (lane & 7);
                bfr[nj] = *(const bf16x8*)&Bs[row * 64 + cp * 8];
            }
            #pragma unroll
            for (int mi = 0; mi < 4; ++mi)
                #pragma unroll
                for (int nj = 0; nj < NFR; ++nj)
                    acc[mi][nj] = __builtin_amdgcn_mfma_f32_16x16x32_bf16(af[mi], bfr[nj], acc[mi][nj], 0, 0, 0);
        }
        __syncthreads();
    }

    // epilogue: C/D layout col = lane&15, row = (lane>>4)*4 + reg
    #pragma unroll
    for (int mi = 0; mi < 4; ++mi) {
        #pragma unroll
        for (int nj = 0; nj < NFR; ++nj) {
            #pragma unroll
            for (int r = 0; r < 4; ++r) {
                int m = m0 + wm * 64 + mi * 16 + (lane >> 4) * 4 + r;
                int n = n0 + wn * (TN / 2) + nj * 16 + (lane & 15);
                float val = acc[mi][nj][r] + bias[n];
                if (Cf) {
                    Cf[(size_t)m * D_ + n] = val;
                } else {
                    int b = m >> 11, s = m & (S_ - 1);
                    int h = n >> 6,  d = n & 63;
                    C[((((size_t)b * H_ + h) * S_ + s) << 6) + d] = f2bf(val);
                }
            }
        }
    }
}

// ---------------- rank-1 score-term tables via MFMA -------------------------
// qrk[node][r2] = (q[node].rel_k[h][r2])/24 ; rqk[node][r2] = (rel_q[h][r2].k[node])/24
// This is a GEMM: [nodes x 64] x [64 x 16] per head -> use MFMA with the exact
// operand conventions verified in gemm_bf16: A-frag row = lane&15, k-chunk =
// lane>>4 (+4 for ks=1); B-frag row(r2) = lane&15; C/D col = lane&15 = r2,
// row = (lane>>4)*4 + reg. A-frags load straight from global (no LDS).
// Wave = 32 nodes (2 m-frags), block = 128 nodes, 512 blocks (2 waves/SIMD).
__global__ __launch_bounds__(256) void rel_dots(
    const unsigned short* __restrict__ q, const unsigned short* __restrict__ k_,
    const float* __restrict__ rel_q, const float* __restrict__ rel_k,
    float* __restrict__ qrk, float* __restrict__ rqk)
{
    const int t    = threadIdx.x;
    const int lane = t & 63;
    const int w    = t >> 6;
    const int n0   = blockIdx.x * 128 + w * 32;   // wave's 32-node base (never crosses bh)
    const int h    = (n0 >> 11) & 7;
    const int r2   = lane & 15;
    const int ch   = lane >> 4;                   // 0..3: 8-elem k-chunk

    // B fragments for both k-halves, both tables (f32 -> bf16 in-register)
    bf16x8 bk2[2], bq2[2];
    #pragma unroll
    for (int ks = 0; ks < 2; ++ks) {
        const float* pk = rel_k + (((h << 4) + r2) << 6) + ks * 32 + ch * 8;
        const float* pq = rel_q + (((h << 4) + r2) << 6) + ks * 32 + ch * 8;
        f32x4 k0 = *(const f32x4*)pk, k1 = *(const f32x4*)(pk + 4);
        f32x4 q0 = *(const f32x4*)pq, q1 = *(const f32x4*)(pq + 4);
        bf16x8 bk, bq;
        #pragma unroll
        for (int i = 0; i < 4; ++i) {
            bk[i]     = (short)f2bf(k0[i]);
            bk[4 + i] = (short)f2bf(k1[i]);
            bq[i]     = (short)f2bf(q0[i]);
            bq[4 + i] = (short)f2bf(q1[i]);
        }
        bk2[ks] = bk; bq2[ks] = bq;
    }

    f32x4 aq[2] = {{0.f,0.f,0.f,0.f},{0.f,0.f,0.f,0.f}};
    f32x4 ak[2] = {{0.f,0.f,0.f,0.f},{0.f,0.f,0.f,0.f}};
    #pragma unroll
    for (int mi = 0; mi < 2; ++mi) {
        int m = n0 + mi * 16 + r2;               // A-frag row = lane&15
        #pragma unroll
        for (int ks = 0; ks < 2; ++ks) {
            bf16x8 aqf = *(const bf16x8*)&q [((size_t)m << 6) + ks * 32 + ch * 8];
            bf16x8 akf = *(const bf16x8*)&k_[((size_t)m << 6) + ks * 32 + ch * 8];
            aq[mi] = __builtin_amdgcn_mfma_f32_16x16x32_bf16(aqf, bk2[ks], aq[mi], 0, 0, 0);
            ak[mi] = __builtin_amdgcn_mfma_f32_16x16x32_bf16(akf, bq2[ks], ak[mi], 0, 0, 0);
        }
    }
    #pragma unroll
    for (int mi = 0; mi < 2; ++mi) {
        #pragma unroll
        for (int r = 0; r < 4; ++r) {
            int m = n0 + mi * 16 + (ch << 2) + r;
            qrk[((size_t)m << 4) + r2] = aq[mi][r] * SCALE_;
            rqk[((size_t)m << 4) + r2] = ak[mi][r] * SCALE_;
        }
    }
}

// ---------------- fused ELL-build + score+softmax+aggregate -----------------
// One block per (bh, 128-dst window). Scan phase skips the always-masked
// r2==0 range and reads edge indices as int2. Gather phase: slimmed loop —
// score is only q.k (rank-1 terms come from the precomputed tables: qrk via
// per-dst register row + shfl, rqk via 4B L2 gather), rel_v read as f32
// directly from the input (L1-resident), o-accum avoids its conversions.
__global__ __launch_bounds__(1024) void attn_fused(
    const unsigned short* __restrict__ q, const unsigned short* __restrict__ k_,
    const unsigned short* __restrict__ v_,
    const float* __restrict__ qrk, const float* __restrict__ rqk,
    const float* __restrict__ rel_v,
    const int* __restrict__ start_nodes, const int* __restrict__ end_nodes,
    unsigned short* __restrict__ attn)
{
    __shared__ unsigned short ell[128 * ELLCAP];   // 16 KB
    __shared__ int cnt[128];
    const int bi  = blockIdx.x;          // 512 blocks
    const int xcd = bi & 7;
    const int loc = bi >> 3;             // 0..63
    const int bh  = xcd * 4 + (loc >> 4);
    const int dlo = (loc & 15) << 7;     // 128-dst window base
    const int t   = threadIdx.x;

    if (t < 128) cnt[t] = 0;
    __syncthreads();

    // ---- scan phase: coalesced int2 read of this bh's edge lists ----
    const int base_idx = bh * (R_ * S_);
    for (int f = S_ + t * 2; f < EPB; f += 2048) {   // 15 iterations, r2>=1
        int r2 = f >> 11;
        int s  = f & (S_ - 1);                        // even
        int idx = base_idx + ((r2 & 7) << 11) + s;
        int2 sn2 = *(const int2*)&start_nodes[idx];
        int2 en2 = *(const int2*)&end_nodes[idx];
        #pragma unroll
        for (int u = 0; u < 2; ++u) {
            int sn = u ? sn2.y : sn2.x;
            if (sn == -1) continue;                   // padded edge
            int en = u ? en2.y : en2.x;
            int dst = (r2 < R_) ? en : sn;
            unsigned rel = (unsigned)(dst - dlo);
            if (rel < 128u) {
                int ki = (r2 < R_) ? sn : en;
                int pos = atomicAdd(&cnt[rel], 1);
                if (pos < ELLCAP)
                    ell[(rel << 6) + pos] = (unsigned short)((r2 << 11) | ki);
            }
        }
    }
    __syncthreads();

    // ---- gather phase: wave w handles dsts dlo + dd*16 + w ----
    const int w    = t >> 6;
    const int lane = t & 63;
    const int grp  = lane >> 3;          // edge slot within group-of-8
    const int sub  = lane & 7;           // dk chunk (8 elems)
    const int h    = bh & 7;
    const size_t node_base = ((size_t)bh << 11);
    const float* qrk_bh = qrk + (node_base << 4);
    const float* rqk_bh = rqk + (node_base << 4);
    const float* rvh    = rel_v + ((size_t)(h << 4) << 6);   // [16][64] f32

    for (int dd = 0; dd < 8; ++dd) {
        int dl  = dd * 16 + w;           // 0..127
        int dst = dlo + dl;

        ushort8_t q8 = *(const ushort8_t*)&q[((node_base + dst) << 6) + sub * 8];
        float qv[8];
        #pragma unroll
        for (int i = 0; i < 8; ++i) qv[i] = bf2f(q8[i]);
        float qrk_l = qrk_bh[((size_t)dst << 4) + (lane & 15)];  // lanes 0..15 hold r2 row

        int n = cnt[dl];
        if (n > ELLCAP) n = ELLCAP;
        int d_all = (int)ell[(dl << 6) + lane];   // LDS row, 2-way free

        float den = 0.f;
        float o[8] = {};
        #pragma unroll 2
        for (int j = 0; j < n; j += 8) {
            int slot = j + grp;
            int d = __shfl(d_all, slot);
            bool valid = slot < n;
            int ki = d & (S_ - 1);
            int r2 = (d >> 11) & 15;
            ushort8_t k8 = *(const ushort8_t*)&k_[((node_base + ki) << 6) + sub * 8];
            float p = 0.f;
            #pragma unroll
            for (int i = 0; i < 8; ++i)
                p = fmaf(bf2f(k8[i]), qv[i], p);
            p += __shfl_xor(p, 1);
            p += __shfl_xor(p, 2);
            p += __shfl_xor(p, 4);
            float tb = __shfl(qrk_l, r2) + rqk_bh[((size_t)ki << 4) + r2];
            float sf = valid ? __expf(fmaf(p, SCALE_, tb)) : 0.f;
            ushort8_t v8 = *(const ushort8_t*)&v_[((node_base + ki) << 6) + sub * 8];
            const float* rvp = rvh + (r2 << 6) + sub * 8;
            f32x4 rv0 = *(const f32x4*)rvp;
            f32x4 rv1 = *(const f32x4*)(rvp + 4);
            den += sf;
            #pragma unroll
            for (int i = 0; i < 4; ++i)
                o[i] = fmaf(sf, bf2f(v8[i]) + rv0[i], o[i]);
            #pragma unroll
            for (int i = 0; i < 4; ++i)
                o[4 + i] = fmaf(sf, bf2f(v8[4 + i]) + rv1[i], o[4 + i]);
        }
        // cross-group reduction (xor 8,16,32 preserves sub)
        den += __shfl_xor(den, 8); den += __shfl_xor(den, 16); den += __shfl_xor(den, 32);
        #pragma unroll
        for (int i = 0; i < 8; ++i) {
            o[i] += __shfl_xor(o[i], 8);
            o[i] += __shfl_xor(o[i], 16);
            o[i] += __shfl_xor(o[i], 32);
        }
        if (grp == 0) {
            float inv = (den > 0.f) ? 1.0f / den : 0.f;
            ushort8_t r;
            #pragma unroll
            for (int i = 0; i < 8; ++i) r[i] = f2bf(o[i] * inv);
            *(ushort8_t*)&attn[((node_base + dst) << 6) + sub * 8] = r;
        }
    }
}

extern "C" void kernel_launch(void* const* d_in, const int* in_sizes, int n_in,
                              void* d_out, int out_size, void* d_ws, size_t ws_size,
                              hipStream_t stream) {
    const float* query = (const float*)d_in[0];
    const float* key   = (const float*)d_in[1];
    const float* value = (const float*)d_in[2];
    const int* start_nodes = (const int*)d_in[3];
    const int* end_nodes   = (const int*)d_in[4];
    const float* rel_q = (const float*)d_in[5];
    const float* rel_k = (const float*)d_in[6];
    const float* rel_v = (const float*)d_in[7];
    const float* Wq = (const float*)d_in[8];
    const float* bq = (const float*)d_in[9];
    const float* Wk = (const float*)d_in[10];
    const float* bk = (const float*)d_in[11];
    const float* Wv = (const float*)d_in[12];
    const float* bv = (const float*)d_in[13];
    const float* Wo = (const float*)d_in[14];
    const float* bo = (const float*)d_in[15];
    float* out = (float*)d_out;

    const size_t NQ = (size_t)B_ * H_ * S_ * DK_;   // 4,194,304
    const size_t NW = (size_t)D_ * D_;              // 262,144
    unsigned short* p = (unsigned short*)d_ws;
    unsigned short* qc = p;            p += NQ;
    unsigned short* kc = p;            p += NQ;
    unsigned short* vc = p;            p += NQ;
    unsigned short* q  = p;            p += NQ;
    unsigned short* k  = p;            p += NQ;
    unsigned short* v  = p;            p += NQ;
    unsigned short* attn = p;          p += NQ;
    unsigned short* wqb = p;           p += NW;
    unsigned short* wkb = p;           p += NW;
    unsigned short* wvb = p;           p += NW;
    unsigned short* wob = p;           p += NW;
    // score-term tables alias qc (dead after GEMM1): 2 x 1M f32 = 8 MB = |qc|
    float* qrk = (float*)qc;
    float* rqk = qrk + ((size_t)1 << 20);

    // 1) fused converts (one dispatch)
    prep<<<13312, 256, 0, stream>>>(query, key, value, Wq, Wk, Wv, Wo,
                                    qc, kc, vc, wqb, wkb, wvb, wob);

    // 2) fused QKV projection (128x128 tiles, 768 blocks)
    dim3 ggrid(B_ * S_ / 128, D_ / 128, 3);
    gemm_bf16<128><<<ggrid, 256, 0, stream>>>(qc, kc, vc, wqb, wkb, wvb, bq, bk, bv,
                                              q, k, v, nullptr, 0);

    // 3) rank-1 score-term tables via MFMA (q.rel_k, rel_q.k), prescaled by 1/24
    rel_dots<<<512, 256, 0, stream>>>(q, k, rel_q, rel_k, qrk, rqk);

    // 4) fused ELL-build + attention (no global ELL)
    attn_fused<<<512, 1024, 0, stream>>>(q, k, v, qrk, rqk, rel_v,
                                         start_nodes, end_nodes, attn);

    // 5) output projection (128x64 tiles -> 512 blocks = 2/CU, fp32 out)
    dim3 ogrid(B_ * S_ / 128, D_ / 64, 1);
    gemm_bf16<64><<<ogrid, 256, 0, stream>>>(attn, attn, attn, wob, wob, wob, bo, bo, bo,
                                             nullptr, nullptr, nullptr, out, 1);
}

// Round 3
// 207.884 us; speedup vs baseline: 1.0988x; 1.0380x over previous
//
#include <hip/hip_runtime.h>
#include <math.h>

// Problem constants (fixed by reference): B=4, S=2048, D=512, H=8, R=8, dk=64
#define B_ 4
#define S_ 2048
#define D_ 512
#define H_ 8
#define R_ 8
#define DK_ 64
#define NEDGE (B_*H_*2*R_*S_)   // 1,048,576
#define EPB   (2*R_*S_)         // 32768 edges per (b,h)
#define ELLCAP 64               // max in-degree slots; Poisson(15) tail ~2e-8
#define ELLSTRIDE 72            // padded row stride (bank-spread + prefetch slack)
#define SCALE_ (1.0f/24.0f)     // 1/(3*sqrt(dk))

typedef __attribute__((ext_vector_type(8))) short bf16x8;
typedef __attribute__((ext_vector_type(8))) unsigned short ushort8_t;
typedef __attribute__((ext_vector_type(4))) float f32x4;

#define AS1q const __attribute__((address_space(1)))
#define AS3q __attribute__((address_space(3)))

__device__ inline unsigned short f2bf(float f) {
    unsigned u = __builtin_bit_cast(unsigned, f);
    u += 0x7fffu + ((u >> 16) & 1u);   // RNE (no NaN inputs here)
    return (unsigned short)(u >> 16);
}
__device__ inline float bf2f(unsigned short u) {
    return __builtin_bit_cast(float, ((unsigned)u) << 16);
}

// ---------------- fused prep: qkv + W converts ------------------------------
__global__ __launch_bounds__(256) void prep(
    const float* __restrict__ query, const float* __restrict__ key,
    const float* __restrict__ value,
    const float* __restrict__ Wq, const float* __restrict__ Wk,
    const float* __restrict__ Wv, const float* __restrict__ Wo,
    unsigned short* __restrict__ qc, unsigned short* __restrict__ kc,
    unsigned short* __restrict__ vc,
    unsigned short* __restrict__ wqb, unsigned short* __restrict__ wkb,
    unsigned short* __restrict__ wvb, unsigned short* __restrict__ wob)
{
    int bid = blockIdx.x;
    const float* x;
    unsigned short* y;
    size_t i;
    if (bid < 12288) {
        int z = bid >> 12;                 // 0..2
        x = (z == 0) ? query : (z == 1) ? key : value;
        y = (z == 0) ? qc : (z == 1) ? kc : vc;
        i = ((size_t)(bid & 4095) * 256 + threadIdx.x) * 4;
    } else {
        int r = bid - 12288;
        int z = r >> 8;                    // 0..3
        x = (z == 0) ? Wq : (z == 1) ? Wk : (z == 2) ? Wv : Wo;
        y = (z == 0) ? wqb : (z == 1) ? wkb : (z == 2) ? wvb : wob;
        i = ((size_t)(r & 255) * 256 + threadIdx.x) * 4;
    }
    float4 v = *(const float4*)&x[i];
    *(ushort4*)&y[i] = make_ushort4(f2bf(v.x), f2bf(v.y), f2bf(v.z), f2bf(v.w));
}

// ---------------- bf16 GEMM, m97-style: global_load_lds + XOR-swizzled LDS --
template<int TN>
__global__ __launch_bounds__(256) void gemm_bf16(
    const unsigned short* __restrict__ A0, const unsigned short* __restrict__ A1,
    const unsigned short* __restrict__ A2,
    const unsigned short* __restrict__ W0, const unsigned short* __restrict__ W1,
    const unsigned short* __restrict__ W2,
    const float* __restrict__ bi0, const float* __restrict__ bi1, const float* __restrict__ bi2,
    unsigned short* __restrict__ C0, unsigned short* __restrict__ C1,
    unsigned short* __restrict__ C2,
    float* __restrict__ Cf, int a_bhsd)
{
    constexpr int NFR = TN / 32;           // B frags per wave (4 or 2)
    __shared__ unsigned short As[128 * 64];
    __shared__ unsigned short Bs[TN * 64];
    const int z = blockIdx.z;
    const unsigned short* A = (z == 0) ? A0 : (z == 1) ? A1 : A2;
    const unsigned short* W = (z == 0) ? W0 : (z == 1) ? W1 : W2;
    const float* bias        = (z == 0) ? bi0 : (z == 1) ? bi1 : bi2;
    unsigned short* C        = (z == 0) ? C0 : (z == 1) ? C1 : C2;

    const int t    = threadIdx.x;
    const int lane = t & 63;
    const int w    = t >> 6;
    const int wm   = w >> 1, wn = w & 1;
    const int m0   = blockIdx.x * 128;
    const int n0   = blockIdx.y * TN;

    const int lr    = lane >> 3;           // row within 8-row stage chunk
    const int cglob = (lane & 7) ^ lr;     // swizzled global source chunk

    f32x4 acc[4][NFR] = {};

    for (int kk = 0; kk < D_; kk += 64) {
        #pragma unroll
        for (int i = 0; i < 4; ++i) {
            int rowl = w * 32 + i * 8;         // wave-uniform LDS row base
            int m = m0 + rowl + lr;
            const unsigned short* ga;
            if (a_bhsd) {
                int b = m >> 11, s = m & (S_ - 1), h = kk >> 6;
                ga = A + ((((size_t)b * H_ + h) * S_ + s) << 6) + cglob * 8;
            } else {
                ga = A + (size_t)m * D_ + kk + cglob * 8;
            }
            __builtin_amdgcn_global_load_lds((AS1q unsigned*)ga,
                (AS3q unsigned*)(As + rowl * 64), 16, 0, 0);
        }
        #pragma unroll
        for (int i = 0; i < TN / 32; ++i) {
            int rowl = w * (TN / 4) + i * 8;
            const unsigned short* gb =
                W + (size_t)(n0 + rowl + lr) * D_ + kk + cglob * 8;
            __builtin_amdgcn_global_load_lds((AS1q unsigned*)gb,
                (AS3q unsigned*)(Bs + rowl * 64), 16, 0, 0);
        }
        __syncthreads();

        #pragma unroll
        for (int ks = 0; ks < 64; ks += 32) {
            const int c0 = ks >> 3;            // 0 or 4
            bf16x8 af[4], bfr[NFR];
            #pragma unroll
            for (int mi = 0; mi < 4; ++mi) {
                int row = wm * 64 + mi * 16 + (lane & 15);
                int cp  = (c0 + (lane >> 4)) ^ (lane & 7);
                af[mi] = *(const bf16x8*)&As[row * 64 + cp * 8];
            }
            #pragma unroll
            for (int nj = 0; nj < NFR; ++nj) {
                int row = wn * (TN / 2) + nj * 16 + (lane & 15);
                int cp  = (c0 + (lane >> 4)) ^ (lane & 7);
                bfr[nj] = *(const bf16x8*)&Bs[row * 64 + cp * 8];
            }
            #pragma unroll
            for (int mi = 0; mi < 4; ++mi)
                #pragma unroll
                for (int nj = 0; nj < NFR; ++nj)
                    acc[mi][nj] = __builtin_amdgcn_mfma_f32_16x16x32_bf16(af[mi], bfr[nj], acc[mi][nj], 0, 0, 0);
        }
        __syncthreads();
    }

    // epilogue: C/D layout col = lane&15, row = (lane>>4)*4 + reg
    #pragma unroll
    for (int mi = 0; mi < 4; ++mi) {
        #pragma unroll
        for (int nj = 0; nj < NFR; ++nj) {
            #pragma unroll
            for (int r = 0; r < 4; ++r) {
                int m = m0 + wm * 64 + mi * 16 + (lane >> 4) * 4 + r;
                int n = n0 + wn * (TN / 2) + nj * 16 + (lane & 15);
                float val = acc[mi][nj][r] + bias[n];
                if (Cf) {
                    Cf[(size_t)m * D_ + n] = val;
                } else {
                    int b = m >> 11, s = m & (S_ - 1);
                    int h = n >> 6,  d = n & 63;
                    C[((((size_t)b * H_ + h) * S_ + s) << 6) + d] = f2bf(val);
                }
            }
        }
    }
}

// ---------------- rank-1 score-term tables via MFMA -------------------------
// qrk[node][r2] = (q[node].rel_k[h][r2])/24 ; rqk[node][r2] = (rel_q[h][r2].k[node])/24
__global__ __launch_bounds__(256) void rel_dots(
    const unsigned short* __restrict__ q, const unsigned short* __restrict__ k_,
    const float* __restrict__ rel_q, const float* __restrict__ rel_k,
    float* __restrict__ qrk, float* __restrict__ rqk)
{
    const int t    = threadIdx.x;
    const int lane = t & 63;
    const int w    = t >> 6;
    const int n0   = blockIdx.x * 128 + w * 32;   // wave's 32-node base (never crosses bh)
    const int h    = (n0 >> 11) & 7;
    const int r2   = lane & 15;
    const int ch   = lane >> 4;                   // 0..3: 8-elem k-chunk

    // B fragments for both k-halves, both tables (f32 -> bf16 in-register)
    bf16x8 bk2[2], bq2[2];
    #pragma unroll
    for (int ks = 0; ks < 2; ++ks) {
        const float* pk = rel_k + (((h << 4) + r2) << 6) + ks * 32 + ch * 8;
        const float* pq = rel_q + (((h << 4) + r2) << 6) + ks * 32 + ch * 8;
        f32x4 k0 = *(const f32x4*)pk, k1 = *(const f32x4*)(pk + 4);
        f32x4 q0 = *(const f32x4*)pq, q1 = *(const f32x4*)(pq + 4);
        bf16x8 bk, bq;
        #pragma unroll
        for (int i = 0; i < 4; ++i) {
            bk[i]     = (short)f2bf(k0[i]);
            bk[4 + i] = (short)f2bf(k1[i]);
            bq[i]     = (short)f2bf(q0[i]);
            bq[4 + i] = (short)f2bf(q1[i]);
        }
        bk2[ks] = bk; bq2[ks] = bq;
    }

    f32x4 aq[2] = {{0.f,0.f,0.f,0.f},{0.f,0.f,0.f,0.f}};
    f32x4 ak[2] = {{0.f,0.f,0.f,0.f},{0.f,0.f,0.f,0.f}};
    #pragma unroll
    for (int mi = 0; mi < 2; ++mi) {
        int m = n0 + mi * 16 + r2;               // A-frag row = lane&15
        #pragma unroll
        for (int ks = 0; ks < 2; ++ks) {
            bf16x8 aqf = *(const bf16x8*)&q [((size_t)m << 6) + ks * 32 + ch * 8];
            bf16x8 akf = *(const bf16x8*)&k_[((size_t)m << 6) + ks * 32 + ch * 8];
            aq[mi] = __builtin_amdgcn_mfma_f32_16x16x32_bf16(aqf, bk2[ks], aq[mi], 0, 0, 0);
            ak[mi] = __builtin_amdgcn_mfma_f32_16x16x32_bf16(akf, bq2[ks], ak[mi], 0, 0, 0);
        }
    }
    #pragma unroll
    for (int mi = 0; mi < 2; ++mi) {
        #pragma unroll
        for (int r = 0; r < 4; ++r) {
            int m = n0 + mi * 16 + (ch << 2) + r;
            qrk[((size_t)m << 4) + r2] = aq[mi][r] * SCALE_;
            rqk[((size_t)m << 4) + r2] = ak[mi][r] * SCALE_;
        }
    }
}

// ---------------- fused ELL-build + score+softmax+aggregate -----------------
// One block per (bh, 128-dst window). Scan: coalesced int2 reads, r2>=1 only.
// Gather (restructured): each 8-lane group owns ONE dst entirely -> sf is
// uniform in-group after the 3-shfl p-reduce, each lane accumulates its own
// 8 dims, so NO cross-group epilogue reduce (was 27 shfls/dst) and all 8
// lanes store. 1-deep software pipeline: next edge's d/k8/v8/tb issued while
// current edge computes (d comes straight from the padded LDS ELL row).
__global__ __launch_bounds__(1024) void attn_fused(
    const unsigned short* __restrict__ q, const unsigned short* __restrict__ k_,
    const unsigned short* __restrict__ v_,
    const float* __restrict__ qrk, const float* __restrict__ rqk,
    const float* __restrict__ rel_v,
    const int* __restrict__ start_nodes, const int* __restrict__ end_nodes,
    unsigned short* __restrict__ attn)
{
    __shared__ unsigned short ell[128 * ELLSTRIDE];   // 18 KB
    __shared__ int cnt[128];
    const int bi  = blockIdx.x;          // 512 blocks
    const int xcd = bi & 7;
    const int loc = bi >> 3;             // 0..63
    const int bh  = xcd * 4 + (loc >> 4);
    const int dlo = (loc & 15) << 7;     // 128-dst window base
    const int t   = threadIdx.x;

    if (t < 128) cnt[t] = 0;
    __syncthreads();

    // ---- scan phase: coalesced int2 read of this bh's edge lists ----
    const int base_idx = bh * (R_ * S_);
    for (int f = S_ + t * 2; f < EPB; f += 2048) {   // 15 iterations, r2>=1
        int r2 = f >> 11;
        int s  = f & (S_ - 1);                        // even
        int idx = base_idx + ((r2 & 7) << 11) + s;
        int2 sn2 = *(const int2*)&start_nodes[idx];
        int2 en2 = *(const int2*)&end_nodes[idx];
        #pragma unroll
        for (int u = 0; u < 2; ++u) {
            int sn = u ? sn2.y : sn2.x;
            if (sn == -1) continue;                   // padded edge
            int en = u ? en2.y : en2.x;
            int dst = (r2 < R_) ? en : sn;
            unsigned rel = (unsigned)(dst - dlo);
            if (rel < 128u) {
                int ki = (r2 < R_) ? sn : en;
                int pos = atomicAdd(&cnt[rel], 1);
                if (pos < ELLCAP)
                    ell[rel * ELLSTRIDE + pos] = (unsigned short)((r2 << 11) | ki);
            }
        }
    }
    __syncthreads();

    // ---- gather phase: group g of wave w owns dst dlo + w*8 + g ----
    const int w    = t >> 6;
    const int lane = t & 63;
    const int g    = lane >> 3;          // group (dst) within wave
    const int sub  = lane & 7;           // dk chunk (8 elems)
    const int dl   = w * 8 + g;          // 0..127
    const int dst  = dlo + dl;
    const int h    = bh & 7;
    const size_t node_base = ((size_t)bh << 11);
    const float* qrk_bh = qrk + (node_base << 4);
    const float* rqk_bh = rqk + (node_base << 4);
    const float* rvh    = rel_v + ((size_t)(h << 4) << 6);   // [16][64] f32

    ushort8_t q8 = *(const ushort8_t*)&q[((node_base + dst) << 6) + sub * 8];
    float qv[8];
    #pragma unroll
    for (int i = 0; i < 8; ++i) qv[i] = bf2f(q8[i]);
    const float* qrow = qrk_bh + ((size_t)dst << 4);

    int n = cnt[dl];
    if (n > ELLCAP) n = ELLCAP;
    int nmax = n;
    nmax = max(nmax, __shfl_xor(nmax, 8));
    nmax = max(nmax, __shfl_xor(nmax, 16));
    nmax = max(nmax, __shfl_xor(nmax, 32));

    const unsigned short* er = &ell[dl * ELLSTRIDE];

    float den = 0.f;
    float o[8] = {};

    // pipeline prologue: edge 0
    int d0 = er[0];
    int ki = (0 < n) ? (d0 & (S_ - 1)) : 0;
    int r2 = (0 < n) ? ((d0 >> 11) & 15) : 0;
    ushort8_t k8 = *(const ushort8_t*)&k_[((node_base + ki) << 6) + sub * 8];
    ushort8_t v8 = *(const ushort8_t*)&v_[((node_base + ki) << 6) + sub * 8];
    float tb = qrow[r2] + rqk_bh[((size_t)ki << 4) + r2];

    for (int j = 0; j < nmax; ++j) {
        // prefetch edge j+1 (indices clamped -> safe loads; row padded to 72)
        bool vn = (j + 1) < n;
        int dn = er[j + 1];
        int kin = vn ? (dn & (S_ - 1)) : 0;
        int r2n = vn ? ((dn >> 11) & 15) : 0;
        ushort8_t k8n = *(const ushort8_t*)&k_[((node_base + kin) << 6) + sub * 8];
        ushort8_t v8n = *(const ushort8_t*)&v_[((node_base + kin) << 6) + sub * 8];
        float tbn = qrow[r2n] + rqk_bh[((size_t)kin << 4) + r2n];

        // compute edge j
        bool valid = j < n;
        float p = 0.f;
        #pragma unroll
        for (int i = 0; i < 8; ++i)
            p = fmaf(bf2f(k8[i]), qv[i], p);
        p += __shfl_xor(p, 1);
        p += __shfl_xor(p, 2);
        p += __shfl_xor(p, 4);
        float sf = valid ? __expf(fmaf(p, SCALE_, tb)) : 0.f;
        const float* rvp = rvh + (r2 << 6) + sub * 8;
        f32x4 rv0 = *(const f32x4*)rvp;
        f32x4 rv1 = *(const f32x4*)(rvp + 4);
        den += sf;
        #pragma unroll
        for (int i = 0; i < 4; ++i)
            o[i] = fmaf(sf, bf2f(v8[i]) + rv0[i], o[i]);
        #pragma unroll
        for (int i = 0; i < 4; ++i)
            o[4 + i] = fmaf(sf, bf2f(v8[4 + i]) + rv1[i], o[4 + i]);

        // rotate pipeline
        k8 = k8n; v8 = v8n; tb = tbn; r2 = r2n;
    }

    // epilogue: den/o are complete per-lane (sf uniform in-group), no reduce
    float inv = (den > 0.f) ? 1.0f / den : 0.f;
    ushort8_t r;
    #pragma unroll
    for (int i = 0; i < 8; ++i) r[i] = f2bf(o[i] * inv);
    *(ushort8_t*)&attn[((node_base + dst) << 6) + sub * 8] = r;
}

extern "C" void kernel_launch(void* const* d_in, const int* in_sizes, int n_in,
                              void* d_out, int out_size, void* d_ws, size_t ws_size,
                              hipStream_t stream) {
    const float* query = (const float*)d_in[0];
    const float* key   = (const float*)d_in[1];
    const float* value = (const float*)d_in[2];
    const int* start_nodes = (const int*)d_in[3];
    const int* end_nodes   = (const int*)d_in[4];
    const float* rel_q = (const float*)d_in[5];
    const float* rel_k = (const float*)d_in[6];
    const float* rel_v = (const float*)d_in[7];
    const float* Wq = (const float*)d_in[8];
    const float* bq = (const float*)d_in[9];
    const float* Wk = (const float*)d_in[10];
    const float* bk = (const float*)d_in[11];
    const float* Wv = (const float*)d_in[12];
    const float* bv = (const float*)d_in[13];
    const float* Wo = (const float*)d_in[14];
    const float* bo = (const float*)d_in[15];
    float* out = (float*)d_out;

    const size_t NQ = (size_t)B_ * H_ * S_ * DK_;   // 4,194,304
    const size_t NW = (size_t)D_ * D_;              // 262,144
    unsigned short* p = (unsigned short*)d_ws;
    unsigned short* qc = p;            p += NQ;
    unsigned short* kc = p;            p += NQ;
    unsigned short* vc = p;            p += NQ;
    unsigned short* q  = p;            p += NQ;
    unsigned short* k  = p;            p += NQ;
    unsigned short* v  = p;            p += NQ;
    unsigned short* attn = p;          p += NQ;
    unsigned short* wqb = p;           p += NW;
    unsigned short* wkb = p;           p += NW;
    unsigned short* wvb = p;           p += NW;
    unsigned short* wob = p;           p += NW;
    // score-term tables alias qc (dead after GEMM1): 2 x 1M f32 = 8 MB = |qc|
    float* qrk = (float*)qc;
    float* rqk = qrk + ((size_t)1 << 20);

    // 1) fused converts (one dispatch)
    prep<<<13312, 256, 0, stream>>>(query, key, value, Wq, Wk, Wv, Wo,
                                    qc, kc, vc, wqb, wkb, wvb, wob);

    // 2) fused QKV projection (128x128 tiles, 768 blocks)
    dim3 ggrid(B_ * S_ / 128, D_ / 128, 3);
    gemm_bf16<128><<<ggrid, 256, 0, stream>>>(qc, kc, vc, wqb, wkb, wvb, bq, bk, bv,
                                              q, k, v, nullptr, 0);

    // 3) rank-1 score-term tables via MFMA (q.rel_k, rel_q.k), prescaled by 1/24
    rel_dots<<<512, 256, 0, stream>>>(q, k, rel_q, rel_k, qrk, rqk);

    // 4) fused ELL-build + attention (no global ELL)
    attn_fused<<<512, 1024, 0, stream>>>(q, k, v, qrk, rqk, rel_v,
                                         start_nodes, end_nodes, attn);

    // 5) output projection (128x64 tiles -> 512 blocks = 2/CU, fp32 out)
    dim3 ogrid(B_ * S_ / 128, D_ / 64, 1);
    gemm_bf16<64><<<ogrid, 256, 0, stream>>>(attn, attn, attn, wob, wob, wob, bo, bo, bo,
                                             nullptr, nullptr, nullptr, out, 1);
}